// Round 10
// baseline (214.445 us; speedup 1.0000x reference)
//
#include <hip/hip_runtime.h>
#include <cstddef>

typedef __attribute__((ext_vector_type(8))) _Float16 half8;
typedef __attribute__((ext_vector_type(4))) _Float16 half4;
typedef __attribute__((ext_vector_type(4))) float floatx4;

namespace {
constexpr int kH = 128;
constexpr int kTEnc = 50;
constexpr int kTDec = 60;
constexpr int kRows = 32;        // batch rows per block = 2 pipelined groups of 16
constexpr int kThreads = 512;    // 8 waves
constexpr int kBTot = 8192;
constexpr int kWfBytes = 3 * 32 * 5 * 64 * 8 * 2;   // W' frags f16: [mat][gtile][kc][lane][j]
}

__device__ __forceinline__ float fexp2(float x) {   // v_exp_f32: 2^x
    float r; asm("v_exp_f32 %0, %1" : "=v"(r) : "v"(x)); return r;
}
__device__ __forceinline__ float frcp(float x) {    // v_rcp_f32 (~1 ulp)
    float r; asm("v_rcp_f32 %0, %1" : "=v"(r) : "v"(x)); return r;
}
__device__ __forceinline__ float clampf(float x, float lo, float hi) {
    return fminf(fmaxf(x, lo), hi);
}

// W' packed as fp16 MFMA A-fragments, 3 weight sets:
//   mat 0: encoder  [Whh | Wih hi | Wih lo]            (din=6)
//   mat 1: decoder step-1 (unfused)                    (din=2)
//   mat 2: decoder steps 2..60: W~ = decWhh + decWih@projW  (din=0)
// Rows pre-scaled: i,o: +log2e; f: -log2e (exp2(acc)=e^{-f}); g: +2*log2e.
// Bias applied as f32 MFMA C-init: bias_s[mat][512] = sc * b (mat2: b~ fused).
// Fragment element (mat,gtile,kc,lane,j) = W'[gtile*16+(lane&15)][kc*32+(lane>>4)*8+j];
// main kernel uses the SAME (lane,j)->k map for B fragments (permutation-invariant dot).
__global__ void lstm_prep(const float* __restrict__ encWhh, const float* __restrict__ encWih,
                          const float* __restrict__ decWhh, const float* __restrict__ decWih,
                          const float* __restrict__ encbih, const float* __restrict__ encbhh,
                          const float* __restrict__ decbih, const float* __restrict__ decbhh,
                          const float* __restrict__ projW,  const float* __restrict__ projb,
                          _Float16* __restrict__ wf, float* __restrict__ bias_s) {
    int idx = blockIdx.x * 256 + threadIdx.x;   // [mat][gtile][kc][lane]: 3*32*5*64
    const float L2E = 1.4426950408889634f;
    if (idx < 3 * 512) {                        // scaled biases
        int mat = idx / 512, g = idx & 511;
        int gtype = g >> 7;
        float sc = (gtype == 1) ? -L2E : (gtype == 2) ? 2.0f * L2E : L2E;
        float b = (mat == 0) ? (encbih[g] + encbhh[g]) : (decbih[g] + decbhh[g]);
        if (mat == 2) b += decWih[g * 2 + 0] * projb[0] + decWih[g * 2 + 1] * projb[1];
        bias_s[idx] = sc * b;
    }
    if (idx >= 3 * 32 * 5 * 64) return;
    const int lane = idx & 63;
    const int kc   = (idx >> 6) % 5;
    const int gt   = (idx / 320) & 31;
    const int mat  = idx / 10240;
    const float* Whh = (mat == 0) ? encWhh : decWhh;
    const float* Wih = (mat == 0) ? encWih : decWih;
    const int din = (mat == 0) ? 6 : (mat == 1) ? 2 : 0;
    const int g = gt * 16 + (lane & 15);
    const int gtype = g >> 7;                   // 0:i 1:f 2:g 3:o
    const float sc = (gtype == 1) ? -L2E : (gtype == 2) ? 2.0f * L2E : L2E;

    _Float16 vals[8];
    #pragma unroll
    for (int j = 0; j < 8; j++) {
        int k = kc * 32 + (lane >> 4) * 8 + j;
        float v = 0.0f;
        if (k < kH) {
            v = Whh[g * kH + k];
            if (mat == 2)
                v += decWih[g * 2 + 0] * projW[k] + decWih[g * 2 + 1] * projW[kH + k];
            v *= sc;
        } else {
            int kk = k - kH;                    // 0..31
            if (kk < din)                       v = sc * Wih[g * din + kk];         // * x_hi
            else if (kk >= 8 && kk < 8 + din)   v = sc * Wih[g * din + (kk - 8)];   // * x_lo
        }
        vals[j] = (_Float16)v;
    }
    *(half8*)(wf + (size_t)idx * 8) = *(half8*)vals;
}

__global__ __launch_bounds__(kThreads, 2) void lstm_main(
    const float* __restrict__ x,
    const _Float16* __restrict__ wf,
    const float* __restrict__ bias_s,
    const float* __restrict__ projW,
    const float* __restrict__ projb,
    float* __restrict__ out)
{
    __shared__ alignas(16) _Float16 xs[kTEnc][kRows][2][8];  // [t][r][hi/lo][d], 51.2 KB
    __shared__ alignas(16) _Float16 hbuf[2][2][16][kH];      // [group][parity][row][col], 16 KB
    __shared__ alignas(16) _Float16 decf[kRows][2][8];       // dec step-1 input hi/lo frags
    __shared__ alignas(16) _Float16 zeros16[8];
    __shared__ alignas(8)  float partial[2][8][16][2];       // [group][wv][r][j]
    __shared__ float pb_s[2];

    const int tid  = threadIdx.x;
    const int lane = tid & 63;
    const int wv   = tid >> 6;        // wave: owns gate-cols [16wv,16wv+16) of each gate
    const int l15  = lane & 15;
    const int l4   = lane >> 4;
    const int rowBase = blockIdx.x * kRows;

    // ---- one-time staging ----
    for (int i = tid; i < kTEnc * kRows * 8; i += kThreads) {
        int d = i & 7;
        int r = (i >> 3) & (kRows - 1);
        int t = i >> 8;
        float v = (d < 6) ? x[(size_t)(rowBase + r) * (kTEnc * 6) + t * 6 + d] : 0.0f;
        _Float16 hi = (_Float16)v;
        xs[t][r][0][d] = hi;
        xs[t][r][1][d] = (_Float16)(v - (float)hi);
    }
    for (int i = tid; i < 2 * 2 * 16 * kH; i += kThreads)
        (&hbuf[0][0][0][0])[i] = (_Float16)0.0f;
    {   // decf = x[:, -1, :2] hi/lo (512 threads = 512 slots exactly)
        int r = tid >> 4, hl = (tid >> 3) & 1, d = tid & 7;
        float v = (d < 2) ? x[(size_t)(rowBase + r) * (kTEnc * 6) + (kTEnc - 1) * 6 + d] : 0.0f;
        _Float16 hi = (_Float16)v;
        decf[r][hl][d] = hl ? (_Float16)(v - (float)hi) : hi;
    }
    if (tid < 8) zeros16[tid] = (_Float16)0.0f;
    if (tid < 2) pb_s[tid] = projb[tid];

    // per-lane projW slice (4 gate-cols owned by this lane; shared by both groups)
    floatx4 pwr[2];
    #pragma unroll
    for (int j = 0; j < 2; j++)
        pwr[j] = *(const floatx4*)(projW + j * kH + wv * 16 + l4 * 4);

    // ---- per-wave register-resident weights + f32 bias ----
    half8  wfr[4][5];   // [gate-type][kchunk] -> unified RF (AGPR side)
    floatx4 bs4[4];     // scaled bias (MFMA C-init)
    auto load_wb = [&](int mat) {
        #pragma unroll
        for (int gt = 0; gt < 4; gt++) {
            #pragma unroll
            for (int kc = 0; kc < 5; kc++) {
                size_t off = ((((size_t)mat * 32 + (gt * 8 + wv)) * 5 + kc) * 64 + lane) * 8;
                wfr[gt][kc] = *(const half8*)(wf + off);
            }
            bs4[gt] = *(const floatx4*)(bias_s + mat * 512 + gt * kH + wv * 16 + l4 * 4);
        }
    };
    load_wb(0);
    __syncthreads();

    float cst[2][4] = {};   // cell state per (group, owned col)
    float hreg[2][4];       // f32 h_new (for projection)
    floatx4 acc[2][4];      // gate accs per group (pipelined)
    half8 bfr[4];           // h B-fragments (one group in flight at a time)
    half8 bx;               // x B-fragment
    int rd[2] = {0, 0};     // current read-parity byte offset per group (0 / 4096)

    const int swz = (l15 & 7) << 4;
    int hoffs[4];
    #pragma unroll
    for (int kc = 0; kc < 4; kc++)
        hoffs[kc] = (l15 * 256 + kc * 64 + l4 * 16) ^ swz;   // ds_read_b128
    const int woff = (l15 * 256 + wv * 32 + l4 * 8) ^ swz;   // ds_write_b64

    // x B-frag addresses: l4=0 -> hi, l4=1 -> lo, l4>=2 -> zeros (W' cols are 0 there)
    const char* encXbase = (l4 < 2) ? ((const char*)xs + l15 * 32 + l4 * 16) : (const char*)zeros16;
    const int   encXstep = (l4 < 2) ? (kRows * 2 * 8 * 2) : 0;   // 1024 B per t
    const int   xgoff    = (l4 < 2) ? 512 : 0;                    // group-1 row offset
    const char* decXbase = (l4 < 2) ? ((const char*)decf + l15 * 32 + l4 * 16) : (const char*)zeros16;

    constexpr float kK2 = 2.8853900817779268f;   // 2*log2(e)

    auto LOADS = [&](int g) {     // read h(g) from current parity
        const char* b = (const char*)hbuf + g * 8192 + rd[g];
        #pragma unroll
        for (int kc = 0; kc < 4; kc++)
            bfr[kc] = *(const half8*)(b + hoffs[kc]);
    };
    auto MFMA = [&](int g, bool hasX) {
        #pragma unroll
        for (int gt = 0; gt < 4; gt++) {
            floatx4 a = __builtin_amdgcn_mfma_f32_16x16x32_f16(wfr[gt][0], bfr[0], bs4[gt], 0, 0, 0);
            a = __builtin_amdgcn_mfma_f32_16x16x32_f16(wfr[gt][1], bfr[1], a, 0, 0, 0);
            a = __builtin_amdgcn_mfma_f32_16x16x32_f16(wfr[gt][2], bfr[2], a, 0, 0, 0);
            a = __builtin_amdgcn_mfma_f32_16x16x32_f16(wfr[gt][3], bfr[3], a, 0, 0, 0);
            if (hasX)
                a = __builtin_amdgcn_mfma_f32_16x16x32_f16(wfr[gt][4], bx, a, 0, 0, 0);
            acc[g][gt] = a;
        }
    };
    // Activation for group g (acc from the previous half-step -> MFMA latency hidden).
    // Writes h_new to the OPPOSITE parity, then flips: WAR slack >= 3 barriers.
    auto ACT = [&](int g) {
        half4 pH;
        #pragma unroll
        for (int jj = 0; jj < 4; jj++) {
            float ai   = clampf(acc[g][0][jj], -40.0f, 40.0f);
            float af   = clampf(acc[g][1][jj], -40.0f, 40.0f);
            float ag   = clampf(acc[g][2][jj], -40.0f, 40.0f);
            float ao   = clampf(acc[g][3][jj], -40.0f, 40.0f);
            float e_i  = fexp2(ai);
            float e_mf = fexp2(af);
            float e_g  = fexp2(ag);
            float A    = (1.0f + e_i) * (1.0f + e_g);
            float r1   = frcp(A * (1.0f + e_mf));
            float cn   = r1 * fmaf(e_i * (e_g - 1.0f), 1.0f + e_mf, A * cst[g][jj]);
            cst[g][jj] = cn;
            float e_o  = fexp2(ao);
            float e_c  = fexp2(kK2 * clampf(cn, -30.0f, 30.0f));
            float r2   = frcp((1.0f + e_o) * (1.0f + e_c));
            float hn   = e_o * (e_c - 1.0f) * r2;
            hreg[g][jj] = hn;
            pH[jj] = (_Float16)hn;
        }
        *(half4*)((char*)hbuf + g * 8192 + (rd[g] ^ 4096) + woff) = pH;
        rd[g] ^= 4096;
    };
    auto PROJ = [&](int g) {
        float pp0 = hreg[g][0] * pwr[0][0] + hreg[g][1] * pwr[0][1]
                  + hreg[g][2] * pwr[0][2] + hreg[g][3] * pwr[0][3];
        float pp1 = hreg[g][0] * pwr[1][0] + hreg[g][1] * pwr[1][1]
                  + hreg[g][2] * pwr[1][2] + hreg[g][3] * pwr[1][3];
        pp0 += __shfl_xor(pp0, 16); pp0 += __shfl_xor(pp0, 32);
        pp1 += __shfl_xor(pp1, 16); pp1 += __shfl_xor(pp1, 32);
        if (l4 == 0) {
            partial[g][wv][l15][0] = pp0;
            partial[g][wv][l15][1] = pp1;
        }
    };
    auto REDUCE = [&](int g, int t) {   // wave 0, off critical path
        if (wv == 0 && lane < 32) {
            int r = lane >> 1, j = lane & 1;
            float s = pb_s[j];
            #pragma unroll
            for (int w8 = 0; w8 < 8; w8++) s += partial[g][w8][r][j];
            out[(size_t)(rowBase + g * 16 + r) * (kTDec * 2) + t * 2 + j] = s;
        }
    };

    // ---- encoder, groups pipelined half a step apart ----
    LOADS(0); bx = *(const half8*)encXbase;                  // g0 step-1 gates (h = 0)
    MFMA(0, true);
    __syncthreads();
    for (int t = 0; t < kTEnc - 1; t++) {
        LOADS(1); bx = *(const half8*)(encXbase + t * encXstep + xgoff);
        ACT(0); MFMA(1, true);     // h0(t+1); g1 gates step t+1
        __syncthreads();
        LOADS(0); bx = *(const half8*)(encXbase + (t + 1) * encXstep);
        ACT(1); MFMA(0, true);     // h1(t+1); g0 gates step t+2
        __syncthreads();
    }
    LOADS(1); bx = *(const half8*)(encXbase + (kTEnc - 1) * encXstep + xgoff);
    ACT(0); MFMA(1, true);         // h0(50); g1 gates step 50
    load_wb(1);
    __syncthreads();

    // ---- decoder step 1 (mat1, input = x[:, -1, :2]) ----
    LOADS(0); bx = *(const half8*)decXbase;
    ACT(1); MFMA(0, true);         // h1(50); g0 gates dec-1
    __syncthreads();
    LOADS(1); bx = *(const half8*)(decXbase + xgoff);
    ACT(0); PROJ(0); MFMA(1, true);   // h0(d1) + pred t=0 g0; g1 gates dec-1
    load_wb(2);
    __syncthreads();

    // ---- decoder fused steps: h-only recurrence, pipelined ----
    for (int d = 1; d < kTDec; d++) {
        LOADS(0); ACT(1); PROJ(1); MFMA(0, false); REDUCE(0, d - 1);
        __syncthreads();
        LOADS(1); ACT(0); PROJ(0); MFMA(1, false); REDUCE(1, d - 1);
        __syncthreads();
    }
    // epilogue: finish group 1's last step, then drain outputs
    ACT(1); PROJ(1);
    __syncthreads();
    REDUCE(0, kTDec - 1);
    REDUCE(1, kTDec - 1);
}

extern "C" void kernel_launch(void* const* d_in, const int* in_sizes, int n_in,
                              void* d_out, int out_size, void* d_ws, size_t ws_size,
                              hipStream_t stream) {
    const float* x      = (const float*)d_in[0];
    const float* encWih = (const float*)d_in[1];
    const float* encWhh = (const float*)d_in[2];
    const float* encbih = (const float*)d_in[3];
    const float* encbhh = (const float*)d_in[4];
    const float* decWih = (const float*)d_in[5];
    const float* decWhh = (const float*)d_in[6];
    const float* decbih = (const float*)d_in[7];
    const float* decbhh = (const float*)d_in[8];
    const float* projW  = (const float*)d_in[9];
    const float* projb  = (const float*)d_in[10];

    _Float16* wfrag = (_Float16*)d_ws;
    float* bias_s = (float*)((char*)d_ws + kWfBytes);
    float* out = (float*)d_out;

    lstm_prep<<<120, 256, 0, stream>>>(encWhh, encWih, decWhh, decWih,
                                       encbih, encbhh, decbih, decbhh,
                                       projW, projb, wfrag, bias_s);
    // 256 blocks x 512 threads (8 waves), 32 rows each -> 1 block/CU, single pass
    lstm_main<<<kBTot / kRows, kThreads, 0, stream>>>(x, wfrag, bias_s, projW, projb, out);
}

// Round 13
// 200.798 us; speedup vs baseline: 1.0680x; 1.0680x over previous
//
#include <hip/hip_runtime.h>
#include <cstddef>

typedef __attribute__((ext_vector_type(8))) _Float16 half8;
typedef __attribute__((ext_vector_type(4))) _Float16 half4;
typedef __attribute__((ext_vector_type(4))) float floatx4;

namespace {
constexpr int kH = 128;
constexpr int kTEnc = 50;
constexpr int kTDec = 60;
constexpr int kRows = 32;        // batch rows per block (2 MFMA B-tiles)
constexpr int kThreads = 512;    // 8 waves
constexpr int kBTot = 8192;
constexpr int kWfBytes = 3 * 32 * 5 * 64 * 8 * 2;   // W' frags f16: [mat][gtile][kc][lane][j]
}

__device__ __forceinline__ float fexp2(float x) {   // v_exp_f32: 2^x
    float r; asm("v_exp_f32 %0, %1" : "=v"(r) : "v"(x)); return r;
}
__device__ __forceinline__ float frcp(float x) {    // v_rcp_f32 (~1 ulp)
    float r; asm("v_rcp_f32 %0, %1" : "=v"(r) : "v"(x)); return r;
}
__device__ __forceinline__ float clampf(float x, float lo, float hi) {  // v_med3_f32
    return fminf(fmaxf(x, lo), hi);
}

// W' packed as fp16 MFMA A-fragments, 3 weight sets:
//   mat 0: encoder  [Whh | Wih hi | Wih lo]            (din=6)
//   mat 1: decoder step-1 (unfused)                    (din=2)
//   mat 2: decoder steps 2..60: W~ = decWhh + decWih@projW  (din=0)
// Rows pre-scaled: i,o: +log2e; f: -log2e (exp2(acc)=e^{-f}); g: +2*log2e.
// Bias applied as f32 acc-init: bias_s[mat][512] = sc * b (mat2: b~ fused).
// Fragment element (mat,gtile,kc,lane,j) = W'[gtile*16+(lane&15)][kc*32+(lane>>4)*8+j];
// main kernel uses the SAME (lane,j)->k map for B fragments (permutation-invariant dot).
__global__ void lstm_prep(const float* __restrict__ encWhh, const float* __restrict__ encWih,
                          const float* __restrict__ decWhh, const float* __restrict__ decWih,
                          const float* __restrict__ encbih, const float* __restrict__ encbhh,
                          const float* __restrict__ decbih, const float* __restrict__ decbhh,
                          const float* __restrict__ projW,  const float* __restrict__ projb,
                          _Float16* __restrict__ wf, float* __restrict__ bias_s) {
    int idx = blockIdx.x * 256 + threadIdx.x;   // [mat][gtile][kc][lane]: 3*32*5*64
    const float L2E = 1.4426950408889634f;
    if (idx < 3 * 512) {                        // scaled biases
        int mat = idx / 512, g = idx & 511;
        int gtype = g >> 7;
        float sc = (gtype == 1) ? -L2E : (gtype == 2) ? 2.0f * L2E : L2E;
        float b = (mat == 0) ? (encbih[g] + encbhh[g]) : (decbih[g] + decbhh[g]);
        if (mat == 2) b += decWih[g * 2 + 0] * projb[0] + decWih[g * 2 + 1] * projb[1];
        bias_s[idx] = sc * b;
    }
    if (idx >= 3 * 32 * 5 * 64) return;
    const int lane = idx & 63;
    const int kc   = (idx >> 6) % 5;
    const int gt   = (idx / 320) & 31;
    const int mat  = idx / 10240;
    const float* Whh = (mat == 0) ? encWhh : decWhh;
    const float* Wih = (mat == 0) ? encWih : decWih;
    const int din = (mat == 0) ? 6 : (mat == 1) ? 2 : 0;
    const int g = gt * 16 + (lane & 15);
    const int gtype = g >> 7;                   // 0:i 1:f 2:g 3:o
    const float sc = (gtype == 1) ? -L2E : (gtype == 2) ? 2.0f * L2E : L2E;

    _Float16 vals[8];
    #pragma unroll
    for (int j = 0; j < 8; j++) {
        int k = kc * 32 + (lane >> 4) * 8 + j;
        float v = 0.0f;
        if (k < kH) {
            v = Whh[g * kH + k];
            if (mat == 2)
                v += decWih[g * 2 + 0] * projW[k] + decWih[g * 2 + 1] * projW[kH + k];
            v *= sc;
        } else {
            int kk = k - kH;                    // 0..31
            if (kk < din)                       v = sc * Wih[g * din + kk];         // * x_hi
            else if (kk >= 8 && kk < 8 + din)   v = sc * Wih[g * din + (kk - 8)];   // * x_lo
        }
        vals[j] = (_Float16)v;
    }
    *(half8*)(wf + (size_t)idx * 8) = *(half8*)vals;
}

__global__ __launch_bounds__(kThreads, 2) void lstm_main(
    const float* __restrict__ x,
    const _Float16* __restrict__ wf,
    const float* __restrict__ bias_s,
    const float* __restrict__ projW,
    const float* __restrict__ projb,
    float* __restrict__ out)
{
    __shared__ alignas(16) _Float16 xs[kTEnc][kRows][2][8];  // [t][r][hi/lo][d], 51.2 KB
    __shared__ alignas(16) _Float16 hbuf[2][kRows][kH];      // h f16, XOR-swizzled, ping-pong
    __shared__ alignas(16) _Float16 decf[kRows][2][8];       // dec step-1 input hi/lo frags
    __shared__ alignas(16) _Float16 zeros16[8];
    __shared__ alignas(8)  float partial[2][8][kRows][2];    // [parity][wv][r][j]
    __shared__ float pb_s[2];

    const int tid  = threadIdx.x;
    const int lane = tid & 63;
    const int wv   = tid >> 6;        // wave: owns gate-cols [16wv,16wv+16) of each gate
    const int l15  = lane & 15;
    const int l4   = lane >> 4;
    const int rowBase = blockIdx.x * kRows;

    // ---- one-time staging ----
    for (int i = tid; i < kTEnc * kRows * 8; i += kThreads) {
        int d = i & 7;
        int r = (i >> 3) & (kRows - 1);
        int t = i >> 8;
        float v = (d < 6) ? x[(size_t)(rowBase + r) * (kTEnc * 6) + t * 6 + d] : 0.0f;
        _Float16 hi = (_Float16)v;
        xs[t][r][0][d] = hi;
        xs[t][r][1][d] = (_Float16)(v - (float)hi);
    }
    for (int i = tid; i < kRows * kH; i += kThreads)
        (&hbuf[0][0][0])[i] = (_Float16)0.0f;
    for (int i = tid; i < kRows * 16; i += kThreads)
        (&decf[0][0][0])[i] = (_Float16)0.0f;
    if (tid < 8)  zeros16[tid] = (_Float16)0.0f;
    if (tid < 2)  pb_s[tid] = projb[tid];

    // per-lane projW slice (4 gate-cols owned by this lane; same for both btiles)
    floatx4 pwr[2];
    #pragma unroll
    for (int j = 0; j < 2; j++)
        pwr[j] = *(const floatx4*)(projW + j * kH + wv * 16 + l4 * 4);

    // ---- per-wave register-resident weights + f32 bias ----
    half8  wfr[4][5];   // [gate-type][kchunk] -> unified RF (AGPR side)
    floatx4 bs4[4];     // scaled bias for this lane's 4 gate-cols
    auto load_wb = [&](int mat) {
        #pragma unroll
        for (int gt = 0; gt < 4; gt++) {
            #pragma unroll
            for (int kc = 0; kc < 5; kc++) {
                size_t off = ((((size_t)mat * 32 + (gt * 8 + wv)) * 5 + kc) * 64 + lane) * 8;
                wfr[gt][kc] = *(const half8*)(wf + off);
            }
            bs4[gt] = *(const floatx4*)(bias_s + mat * 512 + gt * kH + wv * 16 + l4 * 4);
        }
    };
    load_wb(0);
    __syncthreads();

    float cst[2][4];    // cell state per (btile, owned col)
    float hreg[2][4];   // f32 h_new (for projection)
    #pragma unroll
    for (int bt = 0; bt < 2; bt++)
        #pragma unroll
        for (int jj = 0; jj < 4; jj++) cst[bt][jj] = 0.0f;

    const int swz = (l15 & 7) << 4;
    int hoffs[4], woff;
    #pragma unroll
    for (int kc = 0; kc < 4; kc++)
        hoffs[kc] = (l15 * 256 + kc * 64 + l4 * 16) ^ swz;   // ds_read_b128 (+bt*4096)
    woff = (l15 * 256 + wv * 32 + l4 * 8) ^ swz;             // ds_write_b64 (+bt*4096)

    // 5th-chunk B-frag addresses: l4=0 -> x hi, l4=1 -> x lo, l4>=2 -> zeros (W' cols are 0 there)
    const char* encXbase = (l4 < 2) ? ((const char*)xs + l15 * 32 + l4 * 16) : (const char*)zeros16;
    const int   encXstep = (l4 < 2) ? (kRows * 2 * 8 * 2) : 0;   // 1024 B per t
    const int   xbt      = (l4 < 2) ? 512 : 0;                    // btile-1 offset
    const char* decXaddr = (l4 < 2) ? ((const char*)decf + l15 * 32 + l4 * 16) : (const char*)zeros16;

    constexpr float kK2 = 2.8853900817779268f;   // 2*log2(e)

    auto run_step = [&](bool useX, half8 bx0, half8 bx1, int curBuf) {
        floatx4 acc[4][2];
        #pragma unroll
        for (int gt = 0; gt < 4; gt++) { acc[gt][0] = bs4[gt]; acc[gt][1] = bs4[gt]; }

        const char* baseH = (const char*)&hbuf[curBuf][0][0];
        #pragma unroll
        for (int kc = 0; kc < 4; kc++) {
            half8 b0 = *(const half8*)(baseH + hoffs[kc]);
            half8 b1 = *(const half8*)(baseH + hoffs[kc] + 4096);
            #pragma unroll
            for (int gt = 0; gt < 4; gt++) {
                acc[gt][0] = __builtin_amdgcn_mfma_f32_16x16x32_f16(wfr[gt][kc], b0, acc[gt][0], 0, 0, 0);
                acc[gt][1] = __builtin_amdgcn_mfma_f32_16x16x32_f16(wfr[gt][kc], b1, acc[gt][1], 0, 0, 0);
            }
        }
        if (useX) {
            #pragma unroll
            for (int gt = 0; gt < 4; gt++) {
                acc[gt][0] = __builtin_amdgcn_mfma_f32_16x16x32_f16(wfr[gt][4], bx0, acc[gt][0], 0, 0, 0);
                acc[gt][1] = __builtin_amdgcn_mfma_f32_16x16x32_f16(wfr[gt][4], bx1, acc[gt][1], 0, 0, 0);
            }
        }

        // i,f,g,o of the same (row,col) live in this lane; accs pre-scaled so
        // exp2 gives e^i, e^{-f}, e^{2g}, e^o directly.
        // Saturation clamps (exact in f32: sigma/tanh == 1.0f well before these
        // bounds) guarantee every intermediate stays finite -> no inf*0 = NaN.
        char* nH = (char*)&hbuf[curBuf ^ 1][0][0];
        #pragma unroll
        for (int bt = 0; bt < 2; bt++) {
            half4 pH;
            #pragma unroll
            for (int jj = 0; jj < 4; jj++) {
                float ai   = clampf(acc[0][bt][jj], -40.0f, 40.0f);
                float af   = clampf(acc[1][bt][jj], -40.0f, 40.0f);
                float ag   = clampf(acc[2][bt][jj], -40.0f, 40.0f);
                float ao   = clampf(acc[3][bt][jj], -40.0f, 40.0f);
                float e_i  = fexp2(ai);
                float e_mf = fexp2(af);
                float e_g  = fexp2(ag);
                float A    = (1.0f + e_i) * (1.0f + e_g);
                float r1   = frcp(A * (1.0f + e_mf));
                float cn   = r1 * fmaf(e_i * (e_g - 1.0f), 1.0f + e_mf, A * cst[bt][jj]);
                cst[bt][jj] = cn;                         // recurrence keeps exact cn
                float e_o  = fexp2(ao);
                float e_c  = fexp2(kK2 * clampf(cn, -30.0f, 30.0f));   // tanh(+-30)==+-1.0f exactly
                float r2   = frcp((1.0f + e_o) * (1.0f + e_c));
                float hn   = e_o * (e_c - 1.0f) * r2;
                hreg[bt][jj] = hn;
                pH[jj] = (_Float16)hn;
            }
            *(half4*)(nH + woff + bt * 4096) = pH;
        }
    };

    int cur = 0;

    // ---- encoder: 50 steps, one barrier each ----
    for (int t = 0; t < kTEnc; t++) {
        const char* xb = encXbase + t * encXstep;
        half8 bx0 = *(const half8*)xb;
        half8 bx1 = *(const half8*)(xb + xbt);
        run_step(true, bx0, bx1, cur);
        __syncthreads();
        cur ^= 1;
    }

    // projection partial from this lane's 4 cols -> per-wave partial in LDS
    auto proj_partial = [&](int par) {
        #pragma unroll
        for (int bt = 0; bt < 2; bt++) {
            float pp0 = hreg[bt][0] * pwr[0][0] + hreg[bt][1] * pwr[0][1]
                      + hreg[bt][2] * pwr[0][2] + hreg[bt][3] * pwr[0][3];
            float pp1 = hreg[bt][0] * pwr[1][0] + hreg[bt][1] * pwr[1][1]
                      + hreg[bt][2] * pwr[1][2] + hreg[bt][3] * pwr[1][3];
            pp0 += __shfl_xor(pp0, 16); pp0 += __shfl_xor(pp0, 32);
            pp1 += __shfl_xor(pp1, 16); pp1 += __shfl_xor(pp1, 32);
            if (l4 == 0) {
                partial[par][wv][bt * 16 + l15][0] = pp0;
                partial[par][wv][bt * 16 + l15][1] = pp1;
            }
        }
    };
    // wave-0 reduce of the PREVIOUS step's partials (off critical path)
    auto reduce_out = [&](int par, int t) {
        int r = lane >> 1, j = lane & 1;
        float s = pb_s[j];
        #pragma unroll
        for (int w8 = 0; w8 < 8; w8++) s += partial[par][w8][r][j];
        out[(size_t)(rowBase + r) * (kTDec * 2) + t * 2 + j] = s;
    };

    // ---- decoder step 1 (unfused weights, input = x[:, -1, :2]) ----
    load_wb(1);
    if (tid < 2 * kRows) {
        int r = tid >> 1, j = tid & 1;
        decf[r][0][j] = xs[kTEnc - 1][r][0][j];
        decf[r][1][j] = xs[kTEnc - 1][r][1][j];
    }
    __syncthreads();
    {
        half8 bx0 = *(const half8*)decXaddr;
        half8 bx1 = *(const half8*)(decXaddr + xbt);
        run_step(true, bx0, bx1, cur);
        proj_partial(0);
        __syncthreads();
        cur ^= 1;
    }
    load_wb(2);   // fused W~ for steps 2..60 (bias b~ in bs4)

    // ---- decoder steps 2..60: h-only recurrence (16 MFMA) + pipelined projection ----
    half8 dummy = *(const half8*)zeros16;
    for (int t = 1; t < kTDec; t++) {
        if (wv == 0) reduce_out((t - 1) & 1, t - 1);
        run_step(false, dummy, dummy, cur);
        proj_partial(t & 1);
        __syncthreads();
        cur ^= 1;
    }
    if (wv == 0) reduce_out((kTDec - 1) & 1, kTDec - 1);
}

extern "C" void kernel_launch(void* const* d_in, const int* in_sizes, int n_in,
                              void* d_out, int out_size, void* d_ws, size_t ws_size,
                              hipStream_t stream) {
    const float* x      = (const float*)d_in[0];
    const float* encWih = (const float*)d_in[1];
    const float* encWhh = (const float*)d_in[2];
    const float* encbih = (const float*)d_in[3];
    const float* encbhh = (const float*)d_in[4];
    const float* decWih = (const float*)d_in[5];
    const float* decWhh = (const float*)d_in[6];
    const float* decbih = (const float*)d_in[7];
    const float* decbhh = (const float*)d_in[8];
    const float* projW  = (const float*)d_in[9];
    const float* projb  = (const float*)d_in[10];

    _Float16* wfrag = (_Float16*)d_ws;
    float* bias_s = (float*)((char*)d_ws + kWfBytes);
    float* out = (float*)d_out;

    lstm_prep<<<120, 256, 0, stream>>>(encWhh, encWih, decWhh, decWih,
                                       encbih, encbhh, decbih, decbhh,
                                       projW, projb, wfrag, bias_s);
    // 256 blocks x 512 threads (8 waves), 32 rows each -> exactly 1 block/CU, single pass
    lstm_main<<<kBTot / kRows, kThreads, 0, stream>>>(x, wfrag, bias_s, projW, projb, out);
}